// Round 1
// baseline (458.713 us; speedup 1.0000x reference)
//
#include <hip/hip_runtime.h>

#define EPS 2e-5f

// ---------------------------------------------------------------------------
// Pipeline (all fp32):
//   k_setup : zero BN-stat accumulators; build stage-1 effective weights
//             W1t[j][k=(i,s)][col=(o,t)] (9*96*256), masked to |s-t|<=3h, /h.
//   k1      : stage-1 GEMM per (j, 16-batch group) + pool(4,s2) + relu,
//             writes p1[b][o][j][t'] (B,16,9,8) + BN1 sum/sumsq atomics.
//   k_bias  : finalize BN1 -> fold into stage-2 weights:
//             W2s[j][k=(ic,s)][col=(o,t)] = raw*a1[i];  bias2[j][col]=sum raw*d1[i]
//   k2      : stage-2 GEMM per (j, 16-batch group) + bias + pool(4,s2) + relu,
//             writes p2[b][o][j][t'] (B,32,7,4) + BN2 stats.
//   k3      : finalize BN2 -> fold into w3; einsum over (i,k) for j=0..4,
//             /2^j, pool over l=0..2, relu -> act3[b][o*5+j] + BN3 stats.
//   k4      : finalize BN3, apply, 3 FC layers -> out (B,17).
// Workspace (floats): stats(256) | W1t(221184) | W2s(688128) | bias2(1792)
//                     | p1(B*1152) | p2(B*896) | act3 (reuses p1 region... no:
//                     act3 gets its own slice after p2; total ~42 MB).
// ---------------------------------------------------------------------------

__global__ void __launch_bounds__(256) k_setup(const float* __restrict__ w1,
                                               float* __restrict__ W1t,
                                               float* __restrict__ stats) {
    int gid = blockIdx.x * 256 + threadIdx.x;
    if (gid < 256) stats[gid] = 0.f;          // stats1[32] stats2[64] stats3[128]
    if (gid >= 9 * 96 * 256) return;
    int j   = gid / (96 * 256);
    int r   = gid % (96 * 256);
    int k   = r >> 8;          // (i,s)
    int col = r & 255;         // (o,t)
    int o = col >> 4, t = col & 15;
    int i = k >> 4,   s = k & 15;
    int h = 1 << j;
    int d = s - t;
    float val = 0.f;
    if (d >= -3 * h && d <= 3 * h) {
        float df = (float)d / (float)h;
        #pragma unroll
        for (int m = 0; m < 7; ++m) {
            float hat = fmaxf(0.f, 1.f - fabsf(df - (float)(m - 3)));
            val += w1[(o * 6 + i) * 7 + m] * hat;
        }
        val /= (float)h;
    }
    W1t[gid] = val;
}

__global__ void __launch_bounds__(256) k1(const float* __restrict__ x,
                                          const float* __restrict__ W1t,
                                          float* __restrict__ p1,
                                          float* __restrict__ stats1) {
    int j   = blockIdx.y;
    int b0  = blockIdx.x * 16;
    int col = threadIdx.x;                    // o*16 + t
    const float* Wj = W1t + j * 96 * 256;
    const float* xb = x + (size_t)b0 * 96;
    float acc[16];
    #pragma unroll
    for (int bb = 0; bb < 16; ++bb) acc[bb] = 0.f;
    for (int k = 0; k < 96; ++k) {
        float w = Wj[k * 256 + col];
        #pragma unroll
        for (int bb = 0; bb < 16; ++bb)
            acc[bb] = fmaf(w, xb[bb * 96 + k], acc[bb]);   // xb loads are wave-uniform -> s_load
    }
    __shared__ float z[16 * 256];
    #pragma unroll
    for (int bb = 0; bb < 16; ++bb) z[bb * 256 + col] = acc[bb];
    __syncthreads();
    // pool window 4 stride 2 pad 1 over t (16 -> 8), then relu
    int tp = col & 7, o = (col >> 3) & 15, bhi = col >> 7;
    int lo = max(0, 2 * tp - 1), hi = min(15, 2 * tp + 2);
    float psum = 0.f, pss = 0.f;
    #pragma unroll
    for (int q = 0; q < 8; ++q) {
        int bb = bhi + 2 * q;
        float v = -1e30f;
        for (int t = lo; t <= hi; ++t) v = fmaxf(v, z[bb * 256 + o * 16 + t]);
        v = fmaxf(v, 0.f);
        p1[(size_t)(b0 + bb) * 1152 + o * 72 + j * 8 + tp] = v;
        psum += v; pss += v * v;
    }
    __shared__ float rs[256], rss[256];
    rs[col] = psum; rss[col] = pss;
    __syncthreads();
    if (col < 16) {
        float s = 0.f, ss = 0.f;
        for (int t2 = 0; t2 < 8; ++t2)
            for (int bl = 0; bl < 2; ++bl) {
                int tt = (bl << 7) | (col << 3) | t2;
                s += rs[tt]; ss += rss[tt];
            }
        atomicAdd(&stats1[col], s);
        atomicAdd(&stats1[16 + col], ss);
    }
}

__global__ void __launch_bounds__(384) k_bias(const float* __restrict__ w2,
                                              const float* __restrict__ g1,
                                              const float* __restrict__ b1,
                                              const float* __restrict__ stats1,
                                              float* __restrict__ W2s,
                                              float* __restrict__ bias2,
                                              float invN1) {
    int blk = blockIdx.x;
    int j   = blk >> 8;        // 0..6
    int col = blk & 255;       // o*8 + t
    int o = col >> 3, t = col & 7;
    int k = threadIdx.x;       // 0..383 = ic*8 + s
    int ic = k >> 3, s = k & 7;
    int i = ic / 3, c = ic % 3;
    float mu  = stats1[i] * invN1;
    float var = stats1[16 + i] * invN1 - mu * mu;
    float rsg = rsqrtf(var + EPS);
    float a1  = g1[i] * rsg;
    float d1  = b1[i] - mu * a1;
    int h = 1 << j;
    int d = s - t;
    float raw = 0.f;
    if (d >= -h && d <= h) {
        float df = (float)d / (float)h;
        #pragma unroll
        for (int m = 0; m < 3; ++m) {
            float hat = fmaxf(0.f, 1.f - fabsf(df - (float)(m - 1)));
            raw += w2[((o * 16 + i) * 3 + c) * 3 + m] * hat;
        }
        raw /= (float)h;
    }
    W2s[(j * 384 + k) * 256 + col] = raw * a1;
    __shared__ float red[384];
    red[k] = raw * d1;
    __syncthreads();
    if (k < 128) red[k] += red[k + 128] + red[k + 256];
    __syncthreads();
    for (int st = 64; st >= 1; st >>= 1) {
        if (k < st) red[k] += red[k + st];
        __syncthreads();
    }
    if (k == 0) bias2[j * 256 + col] = red[0];
}

__global__ void __launch_bounds__(256) k2(const float* __restrict__ p1,
                                          const float* __restrict__ W2s,
                                          const float* __restrict__ bias2,
                                          float* __restrict__ p2,
                                          float* __restrict__ stats2) {
    int j   = blockIdx.y;
    int b0  = blockIdx.x * 16;
    int col = threadIdx.x;                    // o*8 + t
    const float* Wj  = W2s + j * 384 * 256;
    const float* p1b = p1 + (size_t)b0 * 1152;
    float acc[16];
    #pragma unroll
    for (int bb = 0; bb < 16; ++bb) acc[bb] = 0.f;
    for (int i = 0; i < 16; ++i)
        for (int c = 0; c < 3; ++c) {
            int rowoff = i * 72 + (j + c) * 8;
            #pragma unroll
            for (int s = 0; s < 8; ++s) {
                float w = Wj[((i * 3 + c) * 8 + s) * 256 + col];
                #pragma unroll
                for (int bb = 0; bb < 16; ++bb)
                    acc[bb] = fmaf(w, p1b[bb * 1152 + rowoff + s], acc[bb]);
            }
        }
    float bias = bias2[j * 256 + col];
    __shared__ float z[16 * 256];
    #pragma unroll
    for (int bb = 0; bb < 16; ++bb) z[bb * 256 + col] = acc[bb] + bias;
    __syncthreads();
    // pool window 4 stride 2 pad 1 over t (8 -> 4), relu
    int tp = col & 3, o = (col >> 2) & 31, bhi = col >> 7;
    int lo = max(0, 2 * tp - 1), hi = min(7, 2 * tp + 2);
    float psum = 0.f, pss = 0.f;
    #pragma unroll
    for (int q = 0; q < 8; ++q) {
        int bb = bhi + 2 * q;
        float v = -1e30f;
        for (int t = lo; t <= hi; ++t) v = fmaxf(v, z[bb * 256 + o * 8 + t]);
        v = fmaxf(v, 0.f);
        p2[(size_t)(b0 + bb) * 896 + o * 28 + j * 4 + tp] = v;
        psum += v; pss += v * v;
    }
    __shared__ float rs[256], rss[256];
    rs[col] = psum; rss[col] = pss;
    __syncthreads();
    if (col < 32) {
        float s = 0.f, ss = 0.f;
        for (int t2 = 0; t2 < 4; ++t2)
            for (int bl = 0; bl < 2; ++bl) {
                int tt = (bl << 7) | (col << 2) | t2;
                s += rs[tt]; ss += rss[tt];
            }
        atomicAdd(&stats2[col], s);
        atomicAdd(&stats2[32 + col], ss);
    }
}

__global__ void __launch_bounds__(256) k3(const float* __restrict__ p2,
                                          const float* __restrict__ w3,
                                          const float* __restrict__ g2,
                                          const float* __restrict__ b2,
                                          const float* __restrict__ stats2,
                                          float* __restrict__ act3,
                                          float* __restrict__ stats3,
                                          float invN2) {
    int b0 = blockIdx.x * 8;
    int o  = threadIdx.x & 63;
    int q  = threadIdx.x >> 6;
    __shared__ float a2s[32], d2s[32];
    __shared__ float wl[64 * 97];             // +1 pad -> 2-way (free) bank aliasing
    for (int idx = threadIdx.x; idx < 6144; idx += 256) {
        int oo = idx / 96, r = idx % 96;
        wl[oo * 97 + r] = w3[idx];            // w3 (64,32,3,1): flat o*96+i*3+k
    }
    if (threadIdx.x < 32) {
        int i = threadIdx.x;
        float mu  = stats2[i] * invN2;
        float var = stats2[32 + i] * invN2 - mu * mu;
        float rsg = rsqrtf(var + EPS);
        a2s[i] = g2[i] * rsg;
        d2s[i] = b2[i] - mu * a2s[i];
    }
    __syncthreads();
    float w[96];
    float bias3 = 0.f;
    #pragma unroll
    for (int i = 0; i < 32; ++i)
        #pragma unroll
        for (int kk = 0; kk < 3; ++kk) {
            int r = i * 3 + kk;
            float wv = wl[o * 97 + r];
            bias3 = fmaf(wv, d2s[i], bias3);
            w[r]  = wv * a2s[i];
        }
    float psum = 0.f, pss = 0.f;
    for (int bq = 0; bq < 2; ++bq) {
        int b = b0 + q + 4 * bq;
        const float* pb = p2 + (size_t)b * 896;
        for (int j = 0; j < 5; ++j) {
            float l0 = bias3, l1 = bias3, l2 = bias3;   // l=3 is dropped by pool
            #pragma unroll
            for (int i = 0; i < 32; ++i)
                #pragma unroll
                for (int kk = 0; kk < 3; ++kk) {
                    const float* src = pb + i * 28 + (j + kk) * 4;  // uniform -> s_load
                    float wv = w[i * 3 + kk];
                    l0 = fmaf(wv, src[0], l0);
                    l1 = fmaf(wv, src[1], l1);
                    l2 = fmaf(wv, src[2], l2);
                }
            float inv = 1.f / (float)(1 << j);
            float v = fmaxf(0.f, fmaxf(fmaxf(l0, l1), l2) * inv);
            act3[(size_t)b * 320 + o * 5 + j] = v;
            psum += v; pss += v * v;
        }
    }
    __shared__ float rs[256], rss[256];
    rs[threadIdx.x] = psum; rss[threadIdx.x] = pss;
    __syncthreads();
    if (threadIdx.x < 64) {
        float s = 0.f, ss = 0.f;
        for (int qq = 0; qq < 4; ++qq) {
            int tt = (qq << 6) | threadIdx.x;
            s += rs[tt]; ss += rss[tt];
        }
        atomicAdd(&stats3[threadIdx.x], s);
        atomicAdd(&stats3[64 + threadIdx.x], ss);
    }
}

__global__ void __launch_bounds__(256) k4(const float* __restrict__ act3,
                                          const float* __restrict__ g3,
                                          const float* __restrict__ b3,
                                          const float* __restrict__ stats3,
                                          const float* __restrict__ fw1,
                                          const float* __restrict__ fb1,
                                          const float* __restrict__ fw2,
                                          const float* __restrict__ fb2,
                                          const float* __restrict__ fw3,
                                          const float* __restrict__ fb3,
                                          float* __restrict__ out,
                                          float invN3) {
    int b0 = blockIdx.x * 16;
    int bl = threadIdx.x >> 4, f = threadIdx.x & 15;
    __shared__ float a3s[64], d3s[64];
    if (threadIdx.x < 64) {
        int i = threadIdx.x;
        float mu  = stats3[i] * invN3;
        float var = stats3[64 + i] * invN3 - mu * mu;
        float rsg = rsqrtf(var + EPS);
        a3s[i] = g3[i] * rsg;
        d3s[i] = b3[i] - mu * a3s[i];
    }
    __syncthreads();
    int b = b0 + bl;
    const float* ab = act3 + (size_t)b * 320;
    float h1 = fb1[f];
    for (int o = 0; o < 64; ++o) {
        float ao = a3s[o], dd = d3s[o];
        #pragma unroll
        for (int jj = 0; jj < 5; ++jj) {
            int n = o * 5 + jj;
            h1 = fmaf(fw1[f * 320 + n], fmaf(ao, ab[n], dd), h1);
        }
    }
    __shared__ float buf[16 * 17];
    buf[bl * 17 + f] = h1;
    __syncthreads();
    float h2 = fb2[f];
    #pragma unroll
    for (int n = 0; n < 16; ++n) h2 = fmaf(fw2[f * 16 + n], buf[bl * 17 + n], h2);
    __syncthreads();
    buf[bl * 17 + f] = h2;
    __syncthreads();
    float o1 = fb3[f];
    #pragma unroll
    for (int n = 0; n < 16; ++n) o1 = fmaf(fw3[f * 16 + n], buf[bl * 17 + n], o1);
    out[(size_t)b * 17 + f] = o1;
    if (f == 0) {
        float o2 = fb3[16];
        #pragma unroll
        for (int n = 0; n < 16; ++n) o2 = fmaf(fw3[16 * 16 + n], buf[bl * 17 + n], o2);
        out[(size_t)b * 17 + 16] = o2;
    }
}

extern "C" void kernel_launch(void* const* d_in, const int* in_sizes, int n_in,
                              void* d_out, int out_size, void* d_ws, size_t ws_size,
                              hipStream_t stream) {
    (void)n_in; (void)out_size; (void)ws_size;
    const float* x   = (const float*)d_in[0];
    const float* w1  = (const float*)d_in[1];
    const float* w2  = (const float*)d_in[2];
    const float* w3  = (const float*)d_in[3];
    const float* g1  = (const float*)d_in[4];
    const float* b1  = (const float*)d_in[5];
    const float* g2  = (const float*)d_in[6];
    const float* b2  = (const float*)d_in[7];
    const float* g3  = (const float*)d_in[8];
    const float* b3  = (const float*)d_in[9];
    const float* fw1 = (const float*)d_in[10];
    const float* fb1 = (const float*)d_in[11];
    const float* fw2 = (const float*)d_in[12];
    const float* fb2 = (const float*)d_in[13];
    const float* fw3 = (const float*)d_in[14];
    const float* fb3 = (const float*)d_in[15];
    float* out = (float*)d_out;

    int B = in_sizes[0] / 96;                 // 4096

    float* ws     = (float*)d_ws;
    float* stats1 = ws;                       // 32
    float* stats2 = ws + 32;                  // 64
    float* stats3 = ws + 96;                  // 128
    float* W1t    = ws + 256;                 // 9*96*256   = 221184
    float* W2s    = W1t + 9 * 96 * 256;       // 7*384*256  = 688128
    float* bias2  = W2s + 7 * 384 * 256;      // 7*256      = 1792
    float* p1     = bias2 + 7 * 256;          // B*1152
    float* p2     = p1 + (size_t)B * 1152;    // B*896
    float* act3   = p2 + (size_t)B * 896;     // B*320

    float invN1 = 1.f / (float)(B * 72);      // B*9*8
    float invN2 = 1.f / (float)(B * 28);      // B*7*4
    float invN3 = 1.f / (float)(B * 5);       // B*5*1

    k_setup<<<864, 256, 0, stream>>>(w1, W1t, ws);
    k1<<<dim3(B / 16, 9), 256, 0, stream>>>(x, W1t, p1, stats1);
    k_bias<<<7 * 256, 384, 0, stream>>>(w2, g1, b1, stats1, W2s, bias2, invN1);
    k2<<<dim3(B / 16, 7), 256, 0, stream>>>(p1, W2s, bias2, p2, stats2);
    k3<<<B / 8, 256, 0, stream>>>(p2, w3, g2, b2, stats2, act3, stats3, invN2);
    k4<<<B / 16, 256, 0, stream>>>(act3, g3, b3, stats3, fw1, fb1, fw2, fb2, fw3, fb3,
                                   out, invN3);
}

// Round 2
// 254.645 us; speedup vs baseline: 1.8014x; 1.8014x over previous
//
#include <hip/hip_runtime.h>

#define EPS 2e-5f

using short8  = __attribute__((ext_vector_type(8))) short;
using floatx4 = __attribute__((ext_vector_type(4))) float;

// round-to-nearest-even fp32 -> bf16 bits
static __device__ inline unsigned short f2bf(float f) {
    unsigned u = __float_as_uint(f);
    u += 0x7fffu + ((u >> 16) & 1u);
    return (unsigned short)(u >> 16);
}

// ---------------------------------------------------------------------------
// MFMA 16x16x32 bf16 operand layouts (HW-verified per guide):
//   A[m][k]: lane l holds m=l&15, k=(l>>4)*8+e, e=0..7  (8 contiguous k = 16B)
//   B[k][n]: lane l holds n=l&15, k=(l>>4)*8+e
//   C/D   : lane l, reg r -> row=(l>>4)*4+r, col=l&15
// Weights & x are PRE-PACKED in fragment order: frag id -> [lane][8] shorts,
// so every operand load is one coalesced 1KB global_load_dwordx4 per wave.
//
// Pipeline:
//   k_setup : zero stats; build W1f (bf16 B-frags, [j][T16][ks3][lane][8]) and
//             xf (bf16 A-frags, [mt][ks3][lane][8]) from w1/x.
//   k1      : MFMA GEMM C[B,256] per j (K=96) + pool(16->8)+relu via shfl,
//             p1 bf16 [b][o][jj][s] + BN1 stats.
//   k_bias  : fold BN1 into stage-2 weights -> W2f bf16 frags
//             [j][T16][ks12][lane][8]; bias2[j][col] = sum raw*d1.
//   k2      : MFMA GEMM per j (K=384, A-frags read straight from p1) + bias
//             + pool(8->4)+relu, p2 fp32 [b][o][j][t'] + BN2 stats.
//   k3      : fold BN2 into w3; einsum j=0..4 + pool + relu + BN3 stats (fp32).
//   k4      : finalize BN3 + 3 FC layers -> out (B,17).
// ---------------------------------------------------------------------------

__global__ void __launch_bounds__(256) k_setup(const float* __restrict__ w1,
                                               const float* __restrict__ x,
                                               unsigned short* __restrict__ W1f,
                                               unsigned short* __restrict__ xf,
                                               float* __restrict__ stats,
                                               int nxf) {
    int gid = blockIdx.x * 256 + threadIdx.x;
    if (gid < 256) stats[gid] = 0.f;
    if (gid < 221184) {                      // 9*16*3*512 W1 fragments
        int j  = gid / 24576;
        int r  = gid % 24576;
        int T  = r / 1536;
        int r2 = r % 1536;
        int ks = r2 / 512;
        int r3 = r2 % 512;
        int lane = r3 >> 3, e = r3 & 7;
        int n  = T * 16 + (lane & 15);
        int kk = ks * 32 + (lane >> 4) * 8 + e;
        int o = n >> 4, t = n & 15;
        int i = kk >> 4, s = kk & 15;
        int h = 1 << j;
        int d = s - t;
        float val = 0.f;
        if (d >= -3 * h && d <= 3 * h) {
            float df = (float)d / (float)h;
            #pragma unroll
            for (int m = 0; m < 7; ++m) {
                float hat = fmaxf(0.f, 1.f - fabsf(df - (float)(m - 3)));
                val += w1[(o * 6 + i) * 7 + m] * hat;
            }
            val /= (float)h;
        }
        W1f[gid] = f2bf(val);
    } else if (gid < 221184 + nxf) {         // x A-fragments
        int g  = gid - 221184;
        int mt = g / 1536;
        int r2 = g % 1536;
        int ks = r2 / 512;
        int r3 = r2 % 512;
        int lane = r3 >> 3, e = r3 & 7;
        int m  = mt * 16 + (lane & 15);
        int kk = ks * 32 + (lane >> 4) * 8 + e;
        xf[g] = f2bf(x[m * 96 + kk]);
    }
}

__global__ void __launch_bounds__(256) k1(const unsigned short* __restrict__ xf,
                                          const unsigned short* __restrict__ W1f,
                                          unsigned short* __restrict__ p1,
                                          float* __restrict__ stats1) {
    int j    = blockIdx.y;
    int wav  = threadIdx.x >> 6;
    int lane = threadIdx.x & 63;
    int msub = wav & 1, nh = wav >> 1;
    int mt   = blockIdx.x * 2 + msub;        // 16-row tile id
    floatx4 z = {0.f, 0.f, 0.f, 0.f};
    floatx4 acc[8];
    #pragma unroll
    for (int T = 0; T < 8; ++T) acc[T] = z;
    const short8* A  = (const short8*)xf + (size_t)mt * 3 * 64;
    const short8* Bj = (const short8*)W1f + (size_t)(j * 16) * 3 * 64;
    #pragma unroll
    for (int ks = 0; ks < 3; ++ks) {
        short8 a = A[ks * 64 + lane];
        #pragma unroll
        for (int T = 0; T < 8; ++T) {
            short8 b = Bj[((nh * 8 + T) * 3 + ks) * 64 + lane];
            acc[T] = __builtin_amdgcn_mfma_f32_16x16x32_bf16(a, b, acc[T], 0, 0, 0);
        }
    }
    __shared__ float ls[32];
    if (threadIdx.x < 32) ls[threadIdx.x] = 0.f;
    __syncthreads();
    int quad = lane >> 4, l15 = lane & 15;
    int mbase = mt * 16 + quad * 4;
    int tp = l15;                            // pooled index, lanes 0..7 active
    bool act = tp < 8;
    int tpe = tp & 7;
    int base = lane & 48;
    int c0 = base + max(2 * tpe - 1, 0);
    int c1 = base + 2 * tpe;
    int c2 = base + 2 * tpe + 1;
    int c3 = base + min(2 * tpe + 2, 15);
    #pragma unroll
    for (int T = 0; T < 8; ++T) {
        int o = nh * 8 + T;
        float psum = 0.f, pss = 0.f;
        #pragma unroll
        for (int r = 0; r < 4; ++r) {
            float v  = acc[T][r];
            float mx = fmaxf(fmaxf(__shfl(v, c0, 64), __shfl(v, c1, 64)),
                             fmaxf(__shfl(v, c2, 64), __shfl(v, c3, 64)));
            mx = fmaxf(mx, 0.f);
            if (act) {
                p1[(size_t)(mbase + r) * 1152 + o * 72 + j * 8 + tp] = f2bf(mx);
                psum += mx; pss += mx * mx;
            }
        }
        #pragma unroll
        for (int m = 32; m >= 1; m >>= 1) {
            psum += __shfl_xor(psum, m, 64);
            pss  += __shfl_xor(pss,  m, 64);
        }
        if (lane == 0) {
            atomicAdd(&ls[o], psum);
            atomicAdd(&ls[16 + o], pss);
        }
    }
    __syncthreads();
    if (threadIdx.x < 16) {
        atomicAdd(&stats1[threadIdx.x], ls[threadIdx.x]);
        atomicAdd(&stats1[16 + threadIdx.x], ls[16 + threadIdx.x]);
    }
}

__global__ void __launch_bounds__(384) k_bias(const float* __restrict__ w2,
                                              const float* __restrict__ g1,
                                              const float* __restrict__ b1,
                                              const float* __restrict__ stats1,
                                              unsigned short* __restrict__ W2f,
                                              float* __restrict__ bias2,
                                              float invN1) {
    int blk = blockIdx.x;
    int j   = blk >> 8;        // 0..6
    int col = blk & 255;       // o*8 + t
    int o = col >> 3, t = col & 7;
    int k = threadIdx.x;       // 0..383 = (i*3+c)*8 + s
    int ic = k >> 3, s = k & 7;
    int i = ic / 3, c = ic % 3;
    float mu  = stats1[i] * invN1;
    float var = stats1[16 + i] * invN1 - mu * mu;
    float rsg = rsqrtf(var + EPS);
    float a1  = g1[i] * rsg;
    float d1  = b1[i] - mu * a1;
    int h = 1 << j;
    int d = s - t;
    float raw = 0.f;
    if (d >= -h && d <= h) {
        float df = (float)d / (float)h;
        #pragma unroll
        for (int m = 0; m < 3; ++m) {
            float hat = fmaxf(0.f, 1.f - fabsf(df - (float)(m - 1)));
            raw += w2[((o * 16 + i) * 3 + c) * 3 + m] * hat;
        }
        raw /= (float)h;
    }
    // fragment store: T=col>>4, lane=(col&15)+((k>>3)&3)*16, ks=k>>5, e=k&7
    {
        int T    = col >> 4;
        int lane = (col & 15) + ((k >> 3) & 3) * 16;
        int ks   = k >> 5;
        int e    = k & 7;
        W2f[(((size_t)(j * 16 + T) * 12 + ks) * 64 + lane) * 8 + e] = f2bf(raw * a1);
    }
    __shared__ float red[384];
    red[k] = raw * d1;
    __syncthreads();
    if (k < 128) red[k] += red[k + 128] + red[k + 256];
    __syncthreads();
    for (int st = 64; st >= 1; st >>= 1) {
        if (k < st) red[k] += red[k + st];
        __syncthreads();
    }
    if (k == 0) bias2[j * 256 + col] = red[0];
}

__global__ void __launch_bounds__(256) k2(const unsigned short* __restrict__ p1,
                                          const unsigned short* __restrict__ W2f,
                                          const float* __restrict__ bias2,
                                          float* __restrict__ p2,
                                          float* __restrict__ stats2) {
    int j    = blockIdx.y;
    int wav  = threadIdx.x >> 6;
    int lane = threadIdx.x & 63;
    int msub = wav & 1, nh = wav >> 1;
    int m0   = (blockIdx.x * 2 + msub) * 16;
    int quad = lane >> 4, l15 = lane & 15;
    floatx4 z = {0.f, 0.f, 0.f, 0.f};
    floatx4 acc[8];
    #pragma unroll
    for (int T = 0; T < 8; ++T) acc[T] = z;
    const short8* Bj = (const short8*)W2f + (size_t)(j * 16) * 12 * 64;
    const unsigned short* Arow = p1 + (size_t)(m0 + l15) * 1152;
    #pragma unroll
    for (int ks = 0; ks < 12; ++ks) {
        int k0 = ks * 32 + quad * 8;
        int i  = k0 / 24;
        int c  = (k0 - i * 24) >> 3;
        short8 a = *(const short8*)(Arow + i * 72 + (j + c) * 8);
        #pragma unroll
        for (int T = 0; T < 8; ++T) {
            short8 b = Bj[((nh * 8 + T) * 12 + ks) * 64 + lane];
            acc[T] = __builtin_amdgcn_mfma_f32_16x16x32_bf16(a, b, acc[T], 0, 0, 0);
        }
    }
    __shared__ float ls[64];
    if (threadIdx.x < 64) ls[threadIdx.x] = 0.f;
    __syncthreads();
    int mbase = m0 + quad * 4;
    int tp  = lane & 7;                      // pooled index, tp<4 active
    bool act = tp < 4;
    int tpe = tp & 3;
    int base = lane & 56;
    int c0 = base + max(2 * tpe - 1, 0);
    int c1 = base + 2 * tpe;
    int c2 = base + 2 * tpe + 1;
    int c3 = base + min(2 * tpe + 2, 7);
    #pragma unroll
    for (int T = 0; T < 8; ++T) {
        int n = (nh * 8 + T) * 16 + l15;     // col = o*8+t
        int o = n >> 3;
        float bias = bias2[j * 256 + n];
        float psum = 0.f, pss = 0.f;
        #pragma unroll
        for (int r = 0; r < 4; ++r) {
            float v  = acc[T][r] + bias;
            float mx = fmaxf(fmaxf(__shfl(v, c0, 64), __shfl(v, c1, 64)),
                             fmaxf(__shfl(v, c2, 64), __shfl(v, c3, 64)));
            mx = fmaxf(mx, 0.f);
            if (act) {
                p2[(size_t)(mbase + r) * 896 + o * 28 + j * 4 + tp] = mx;
                psum += mx; pss += mx * mx;
            }
        }
        // reduce over the 32 lanes sharing (lane&8) (same o)
        #pragma unroll
        for (int m = 0; m < 5; ++m) {
            int msk = (m < 3) ? (1 << m) : (1 << (m + 1));   // 1,2,4,16,32
            psum += __shfl_xor(psum, msk, 64);
            pss  += __shfl_xor(pss,  msk, 64);
        }
        if (lane == 0 || lane == 8) {
            int oo = (nh * 8 + T) * 2 + (lane >> 3);
            atomicAdd(&ls[oo], psum);
            atomicAdd(&ls[32 + oo], pss);
        }
    }
    __syncthreads();
    if (threadIdx.x < 32) {
        atomicAdd(&stats2[threadIdx.x], ls[threadIdx.x]);
        atomicAdd(&stats2[32 + threadIdx.x], ls[32 + threadIdx.x]);
    }
}

__global__ void __launch_bounds__(256) k3(const float* __restrict__ p2,
                                          const float* __restrict__ w3,
                                          const float* __restrict__ g2,
                                          const float* __restrict__ b2,
                                          const float* __restrict__ stats2,
                                          float* __restrict__ act3,
                                          float* __restrict__ stats3,
                                          float invN2) {
    int b0 = blockIdx.x * 8;
    int o  = threadIdx.x & 63;
    int q  = threadIdx.x >> 6;
    __shared__ float a2s[32], d2s[32];
    __shared__ float wl[64 * 97];
    for (int idx = threadIdx.x; idx < 6144; idx += 256) {
        int oo = idx / 96, r = idx % 96;
        wl[oo * 97 + r] = w3[idx];
    }
    if (threadIdx.x < 32) {
        int i = threadIdx.x;
        float mu  = stats2[i] * invN2;
        float var = stats2[32 + i] * invN2 - mu * mu;
        float rsg = rsqrtf(var + EPS);
        a2s[i] = g2[i] * rsg;
        d2s[i] = b2[i] - mu * a2s[i];
    }
    __syncthreads();
    float w[96];
    float bias3 = 0.f;
    #pragma unroll
    for (int i = 0; i < 32; ++i)
        #pragma unroll
        for (int kk = 0; kk < 3; ++kk) {
            int r = i * 3 + kk;
            float wv = wl[o * 97 + r];
            bias3 = fmaf(wv, d2s[i], bias3);
            w[r]  = wv * a2s[i];
        }
    float psum = 0.f, pss = 0.f;
    for (int bq = 0; bq < 2; ++bq) {
        int b = b0 + q + 4 * bq;
        const float* pb = p2 + (size_t)b * 896;
        for (int j = 0; j < 5; ++j) {
            float l0 = bias3, l1 = bias3, l2 = bias3;
            #pragma unroll
            for (int i = 0; i < 32; ++i)
                #pragma unroll
                for (int kk = 0; kk < 3; ++kk) {
                    const float* src = pb + i * 28 + (j + kk) * 4;
                    float wv = w[i * 3 + kk];
                    l0 = fmaf(wv, src[0], l0);
                    l1 = fmaf(wv, src[1], l1);
                    l2 = fmaf(wv, src[2], l2);
                }
            float inv = 1.f / (float)(1 << j);
            float v = fmaxf(0.f, fmaxf(fmaxf(l0, l1), l2) * inv);
            act3[(size_t)b * 320 + o * 5 + j] = v;
            psum += v; pss += v * v;
        }
    }
    __shared__ float rs[256], rss[256];
    rs[threadIdx.x] = psum; rss[threadIdx.x] = pss;
    __syncthreads();
    if (threadIdx.x < 64) {
        float s = 0.f, ss = 0.f;
        for (int qq = 0; qq < 4; ++qq) {
            int tt = (qq << 6) | threadIdx.x;
            s += rs[tt]; ss += rss[tt];
        }
        atomicAdd(&stats3[threadIdx.x], s);
        atomicAdd(&stats3[64 + threadIdx.x], ss);
    }
}

__global__ void __launch_bounds__(256) k4(const float* __restrict__ act3,
                                          const float* __restrict__ g3,
                                          const float* __restrict__ b3,
                                          const float* __restrict__ stats3,
                                          const float* __restrict__ fw1,
                                          const float* __restrict__ fb1,
                                          const float* __restrict__ fw2,
                                          const float* __restrict__ fb2,
                                          const float* __restrict__ fw3,
                                          const float* __restrict__ fb3,
                                          float* __restrict__ out,
                                          float invN3) {
    int b0 = blockIdx.x * 16;
    int bl = threadIdx.x >> 4, f = threadIdx.x & 15;
    __shared__ float a3s[64], d3s[64];
    if (threadIdx.x < 64) {
        int i = threadIdx.x;
        float mu  = stats3[i] * invN3;
        float var = stats3[64 + i] * invN3 - mu * mu;
        float rsg = rsqrtf(var + EPS);
        a3s[i] = g3[i] * rsg;
        d3s[i] = b3[i] - mu * a3s[i];
    }
    __syncthreads();
    int b = b0 + bl;
    const float* ab = act3 + (size_t)b * 320;
    float h1 = fb1[f];
    for (int o = 0; o < 64; ++o) {
        float ao = a3s[o], dd = d3s[o];
        #pragma unroll
        for (int jj = 0; jj < 5; ++jj) {
            int n = o * 5 + jj;
            h1 = fmaf(fw1[f * 320 + n], fmaf(ao, ab[n], dd), h1);
        }
    }
    __shared__ float buf[16 * 17];
    buf[bl * 17 + f] = h1;
    __syncthreads();
    float h2 = fb2[f];
    #pragma unroll
    for (int n = 0; n < 16; ++n) h2 = fmaf(fw2[f * 16 + n], buf[bl * 17 + n], h2);
    __syncthreads();
    buf[bl * 17 + f] = h2;
    __syncthreads();
    float o1 = fb3[f];
    #pragma unroll
    for (int n = 0; n < 16; ++n) o1 = fmaf(fw3[f * 16 + n], buf[bl * 17 + n], o1);
    out[(size_t)b * 17 + f] = o1;
    if (f == 0) {
        float o2 = fb3[16];
        #pragma unroll
        for (int n = 0; n < 16; ++n) o2 = fmaf(fw3[16 * 16 + n], buf[bl * 17 + n], o2);
        out[(size_t)b * 17 + 16] = o2;
    }
}

extern "C" void kernel_launch(void* const* d_in, const int* in_sizes, int n_in,
                              void* d_out, int out_size, void* d_ws, size_t ws_size,
                              hipStream_t stream) {
    (void)n_in; (void)out_size; (void)ws_size;
    const float* x   = (const float*)d_in[0];
    const float* w1  = (const float*)d_in[1];
    const float* w2  = (const float*)d_in[2];
    const float* w3  = (const float*)d_in[3];
    const float* g1  = (const float*)d_in[4];
    const float* b1  = (const float*)d_in[5];
    const float* g2  = (const float*)d_in[6];
    const float* b2  = (const float*)d_in[7];
    const float* g3  = (const float*)d_in[8];
    const float* b3  = (const float*)d_in[9];
    const float* fw1 = (const float*)d_in[10];
    const float* fb1 = (const float*)d_in[11];
    const float* fw2 = (const float*)d_in[12];
    const float* fb2 = (const float*)d_in[13];
    const float* fw3 = (const float*)d_in[14];
    const float* fb3 = (const float*)d_in[15];
    float* out = (float*)d_out;

    int B = in_sizes[0] / 96;                 // 4096

    char* wsb = (char*)d_ws;
    float*          stats  = (float*)wsb;                    // 256 f (1 KB)
    unsigned short* W1f    = (unsigned short*)(wsb + 1024);  // 221184 us
    unsigned short* xf     = W1f + 221184;                   // B*96 us
    unsigned short* W2f    = xf + (size_t)B * 96;            // 688128 us
    float*          bias2  = (float*)(W2f + 688128);         // 1792 f
    unsigned short* p1     = (unsigned short*)(bias2 + 1792);// B*1152 us
    float*          p2     = (float*)(p1 + (size_t)B * 1152);// B*896 f
    float*          act3   = p2 + (size_t)B * 896;           // B*320 f

    float* stats1 = stats;
    float* stats2 = stats + 32;
    float* stats3 = stats + 96;

    float invN1 = 1.f / (float)(B * 72);
    float invN2 = 1.f / (float)(B * 28);
    float invN3 = 1.f / (float)(B * 5);

    int nxf = B * 96;
    int setup_threads = 221184 + nxf;
    k_setup<<<(setup_threads + 255) / 256, 256, 0, stream>>>(w1, x, W1f, xf, stats, nxf);
    k1<<<dim3(B / 32, 9), 256, 0, stream>>>(xf, W1f, p1, stats1);
    k_bias<<<7 * 256, 384, 0, stream>>>(w2, g1, b1, stats1, W2f, bias2, invN1);
    k2<<<dim3(B / 32, 7), 256, 0, stream>>>(p1, W2f, bias2, p2, stats2);
    k3<<<B / 8, 256, 0, stream>>>(p2, w3, g2, b2, stats2, act3, stats3, invN2);
    k4<<<B / 16, 256, 0, stream>>>(act3, g3, b3, stats3, fw1, fb1, fw2, fb2, fw3, fb3,
                                   out, invN3);
}

// Round 3
// 200.368 us; speedup vs baseline: 2.2894x; 1.2709x over previous
//
#include <hip/hip_runtime.h>

#define EPS 2e-5f

using short8  = __attribute__((ext_vector_type(8))) short;
using floatx4 = __attribute__((ext_vector_type(4))) float;

// round-to-nearest-even fp32 -> bf16 bits
static __device__ inline unsigned short f2bf(float f) {
    unsigned u = __float_as_uint(f);
    u += 0x7fffu + ((u >> 16) & 1u);
    return (unsigned short)(u >> 16);
}

// ---------------------------------------------------------------------------
// MFMA 16x16x32 bf16 operand layouts (HW-verified per guide):
//   A[m][k]: lane l holds m=l&15, k=(l>>4)*8+e, e=0..7  (8 contiguous k = 16B)
//   B[k][n]: lane l holds n=l&15, k=(l>>4)*8+e
//   C/D   : lane l, reg r -> row=(l>>4)*4+r, col=l&15
//
// Pipeline:
//   k_setup : zero stats; W1f bf16 B-frags [j][T16][ks3][lane][8];
//             xf bf16 A-frags [mt][ks3][lane][8].
//   k1      : MFMA GEMM per j (K=96) + pool(16->8)+relu via shfl,
//             p1 bf16 [b][i][jj][s] + BN1 stats.
//   k_bias  : fold BN1 -> W2f bf16 frags [j][T16][ks12][lane][8];
//             bias2[j][col] = sum raw*d1.
//   k2      : MFMA GEMM per j (K=384, A straight from p1) + bias
//             + pool(8->4)+relu -> p2s bf16 [jj][l][b][i] (stage-3 A-layout)
//             + BN2 stats.
//   k_w3    : fold BN2 into w3 -> W3f bf16 B-frags [Tg4][ks3][lane][8];
//             bias3[o] = sum w3*d2.
//   k3      : MFMA GEMM per (j; l=0..2), K=96 -> max over l, *2^-j, relu
//             -> act3[b][o*5+j] + BN3 stats.
//   k4      : finalize BN3 + 3 FC layers -> out (B,17).
// ---------------------------------------------------------------------------

__global__ void __launch_bounds__(256) k_setup(const float* __restrict__ w1,
                                               const float* __restrict__ x,
                                               unsigned short* __restrict__ W1f,
                                               unsigned short* __restrict__ xf,
                                               float* __restrict__ stats,
                                               int nxf) {
    int gid = blockIdx.x * 256 + threadIdx.x;
    if (gid < 256) stats[gid] = 0.f;
    if (gid < 221184) {                      // 9*16*3*512 W1 fragments
        int j  = gid / 24576;
        int r  = gid % 24576;
        int T  = r / 1536;
        int r2 = r % 1536;
        int ks = r2 / 512;
        int r3 = r2 % 512;
        int lane = r3 >> 3, e = r3 & 7;
        int n  = T * 16 + (lane & 15);
        int kk = ks * 32 + (lane >> 4) * 8 + e;
        int o = n >> 4, t = n & 15;
        int i = kk >> 4, s = kk & 15;
        int h = 1 << j;
        int d = s - t;
        float val = 0.f;
        if (d >= -3 * h && d <= 3 * h) {
            float df = (float)d / (float)h;
            #pragma unroll
            for (int m = 0; m < 7; ++m) {
                float hat = fmaxf(0.f, 1.f - fabsf(df - (float)(m - 3)));
                val += w1[(o * 6 + i) * 7 + m] * hat;
            }
            val /= (float)h;
        }
        W1f[gid] = f2bf(val);
    } else if (gid < 221184 + nxf) {         // x A-fragments
        int g  = gid - 221184;
        int mt = g / 1536;
        int r2 = g % 1536;
        int ks = r2 / 512;
        int r3 = r2 % 512;
        int lane = r3 >> 3, e = r3 & 7;
        int m  = mt * 16 + (lane & 15);
        int kk = ks * 32 + (lane >> 4) * 8 + e;
        xf[g] = f2bf(x[m * 96 + kk]);
    }
}

__global__ void __launch_bounds__(256) k1(const unsigned short* __restrict__ xf,
                                          const unsigned short* __restrict__ W1f,
                                          unsigned short* __restrict__ p1,
                                          float* __restrict__ stats1) {
    int j    = blockIdx.y;
    int wav  = threadIdx.x >> 6;
    int lane = threadIdx.x & 63;
    int msub = wav & 1, nh = wav >> 1;
    int mt   = blockIdx.x * 2 + msub;        // 16-row tile id
    floatx4 z = {0.f, 0.f, 0.f, 0.f};
    floatx4 acc[8];
    #pragma unroll
    for (int T = 0; T < 8; ++T) acc[T] = z;
    const short8* A  = (const short8*)xf + (size_t)mt * 3 * 64;
    const short8* Bj = (const short8*)W1f + (size_t)(j * 16) * 3 * 64;
    #pragma unroll
    for (int ks = 0; ks < 3; ++ks) {
        short8 a = A[ks * 64 + lane];
        #pragma unroll
        for (int T = 0; T < 8; ++T) {
            short8 b = Bj[((nh * 8 + T) * 3 + ks) * 64 + lane];
            acc[T] = __builtin_amdgcn_mfma_f32_16x16x32_bf16(a, b, acc[T], 0, 0, 0);
        }
    }
    __shared__ float ls[32];
    if (threadIdx.x < 32) ls[threadIdx.x] = 0.f;
    __syncthreads();
    int quad = lane >> 4, l15 = lane & 15;
    int mbase = mt * 16 + quad * 4;
    int tp = l15;                            // pooled index, lanes 0..7 active
    bool act = tp < 8;
    int tpe = tp & 7;
    int base = lane & 48;
    int c0 = base + max(2 * tpe - 1, 0);
    int c1 = base + 2 * tpe;
    int c2 = base + 2 * tpe + 1;
    int c3 = base + min(2 * tpe + 2, 15);
    #pragma unroll
    for (int T = 0; T < 8; ++T) {
        int o = nh * 8 + T;
        float psum = 0.f, pss = 0.f;
        #pragma unroll
        for (int r = 0; r < 4; ++r) {
            float v  = acc[T][r];
            float mx = fmaxf(fmaxf(__shfl(v, c0, 64), __shfl(v, c1, 64)),
                             fmaxf(__shfl(v, c2, 64), __shfl(v, c3, 64)));
            mx = fmaxf(mx, 0.f);
            if (act) {
                p1[(size_t)(mbase + r) * 1152 + o * 72 + j * 8 + tp] = f2bf(mx);
                psum += mx; pss += mx * mx;
            }
        }
        #pragma unroll
        for (int m = 32; m >= 1; m >>= 1) {
            psum += __shfl_xor(psum, m, 64);
            pss  += __shfl_xor(pss,  m, 64);
        }
        if (lane == 0) {
            atomicAdd(&ls[o], psum);
            atomicAdd(&ls[16 + o], pss);
        }
    }
    __syncthreads();
    if (threadIdx.x < 16) {
        atomicAdd(&stats1[threadIdx.x], ls[threadIdx.x]);
        atomicAdd(&stats1[16 + threadIdx.x], ls[16 + threadIdx.x]);
    }
}

__global__ void __launch_bounds__(384) k_bias(const float* __restrict__ w2,
                                              const float* __restrict__ g1,
                                              const float* __restrict__ b1,
                                              const float* __restrict__ stats1,
                                              unsigned short* __restrict__ W2f,
                                              float* __restrict__ bias2,
                                              float invN1) {
    int blk = blockIdx.x;
    int j   = blk >> 8;        // 0..6
    int col = blk & 255;       // o*8 + t
    int o = col >> 3, t = col & 7;
    int k = threadIdx.x;       // 0..383 = (i*3+c)*8 + s
    int ic = k >> 3, s = k & 7;
    int i = ic / 3, c = ic % 3;
    float mu  = stats1[i] * invN1;
    float var = stats1[16 + i] * invN1 - mu * mu;
    float rsg = rsqrtf(var + EPS);
    float a1  = g1[i] * rsg;
    float d1  = b1[i] - mu * a1;
    int h = 1 << j;
    int d = s - t;
    float raw = 0.f;
    if (d >= -h && d <= h) {
        float df = (float)d / (float)h;
        #pragma unroll
        for (int m = 0; m < 3; ++m) {
            float hat = fmaxf(0.f, 1.f - fabsf(df - (float)(m - 1)));
            raw += w2[((o * 16 + i) * 3 + c) * 3 + m] * hat;
        }
        raw /= (float)h;
    }
    {
        int T    = col >> 4;
        int lane = (col & 15) + ((k >> 3) & 3) * 16;
        int ks   = k >> 5;
        int e    = k & 7;
        W2f[(((size_t)(j * 16 + T) * 12 + ks) * 64 + lane) * 8 + e] = f2bf(raw * a1);
    }
    __shared__ float red[384];
    red[k] = raw * d1;
    __syncthreads();
    if (k < 128) red[k] += red[k + 128] + red[k + 256];
    __syncthreads();
    for (int st = 64; st >= 1; st >>= 1) {
        if (k < st) red[k] += red[k + st];
        __syncthreads();
    }
    if (k == 0) bias2[j * 256 + col] = red[0];
}

__global__ void __launch_bounds__(256) k2(const unsigned short* __restrict__ p1,
                                          const unsigned short* __restrict__ W2f,
                                          const float* __restrict__ bias2,
                                          unsigned short* __restrict__ p2s,
                                          float* __restrict__ stats2,
                                          int B) {
    int j    = blockIdx.y;
    int wav  = threadIdx.x >> 6;
    int lane = threadIdx.x & 63;
    int msub = wav & 1, nh = wav >> 1;
    int m0   = (blockIdx.x * 2 + msub) * 16;
    int quad = lane >> 4, l15 = lane & 15;
    floatx4 z = {0.f, 0.f, 0.f, 0.f};
    floatx4 acc[8];
    #pragma unroll
    for (int T = 0; T < 8; ++T) acc[T] = z;
    const short8* Bj = (const short8*)W2f + (size_t)(j * 16) * 12 * 64;
    const unsigned short* Arow = p1 + (size_t)(m0 + l15) * 1152;
    #pragma unroll
    for (int ks = 0; ks < 12; ++ks) {
        int k0 = ks * 32 + quad * 8;
        int i  = k0 / 24;
        int c  = (k0 - i * 24) >> 3;
        short8 a = *(const short8*)(Arow + i * 72 + (j + c) * 8);
        #pragma unroll
        for (int T = 0; T < 8; ++T) {
            short8 b = Bj[((nh * 8 + T) * 12 + ks) * 64 + lane];
            acc[T] = __builtin_amdgcn_mfma_f32_16x16x32_bf16(a, b, acc[T], 0, 0, 0);
        }
    }
    __shared__ float ls[64];
    if (threadIdx.x < 64) ls[threadIdx.x] = 0.f;
    __syncthreads();
    int mbase = m0 + quad * 4;
    int tp  = lane & 7;                      // pooled index, tp<4 active
    bool act = tp < 4;
    int tpe = tp & 3;
    int base = lane & 56;
    int c0 = base + max(2 * tpe - 1, 0);
    int c1 = base + 2 * tpe;
    int c2 = base + 2 * tpe + 1;
    int c3 = base + min(2 * tpe + 2, 7);
    #pragma unroll
    for (int T = 0; T < 8; ++T) {
        int n = (nh * 8 + T) * 16 + l15;     // col = o*8+t
        int o = n >> 3;
        float bias = bias2[j * 256 + n];
        float psum = 0.f, pss = 0.f;
        #pragma unroll
        for (int r = 0; r < 4; ++r) {
            float v  = acc[T][r] + bias;
            float mx = fmaxf(fmaxf(__shfl(v, c0, 64), __shfl(v, c1, 64)),
                             fmaxf(__shfl(v, c2, 64), __shfl(v, c3, 64)));
            mx = fmaxf(mx, 0.f);
            if (act) {
                // stage-3 A-fragment layout: [jj][l][b][i]
                p2s[(((size_t)j * 4 + tp) * B + mbase + r) * 32 + o] = f2bf(mx);
                psum += mx; pss += mx * mx;
            }
        }
        #pragma unroll
        for (int m = 0; m < 5; ++m) {
            int msk = (m < 3) ? (1 << m) : (1 << (m + 1));   // 1,2,4,16,32
            psum += __shfl_xor(psum, msk, 64);
            pss  += __shfl_xor(pss,  msk, 64);
        }
        if (lane == 0 || lane == 8) {
            int oo = (nh * 8 + T) * 2 + (lane >> 3);
            atomicAdd(&ls[oo], psum);
            atomicAdd(&ls[32 + oo], pss);
        }
    }
    __syncthreads();
    if (threadIdx.x < 32) {
        atomicAdd(&stats2[threadIdx.x], ls[threadIdx.x]);
        atomicAdd(&stats2[32 + threadIdx.x], ls[32 + threadIdx.x]);
    }
}

__global__ void __launch_bounds__(256) k_w3(const float* __restrict__ w3,
                                            const float* __restrict__ g2,
                                            const float* __restrict__ b2,
                                            const float* __restrict__ stats2,
                                            unsigned short* __restrict__ W3f,
                                            float* __restrict__ bias3,
                                            float invN2) {
    __shared__ float a2s[32], d2s[32];
    if (threadIdx.x < 32) {
        int i = threadIdx.x;
        float mu  = stats2[i] * invN2;
        float var = stats2[32 + i] * invN2 - mu * mu;
        float rsg = rsqrtf(var + EPS);
        a2s[i] = g2[i] * rsg;
        d2s[i] = b2[i] - mu * a2s[i];
    }
    __syncthreads();
    for (int idx = threadIdx.x; idx < 6144; idx += 256) {
        int e    = idx & 7;
        int lane = (idx >> 3) & 63;
        int fs   = idx >> 9;               // Tg*3+ks, 0..11
        int Tg = fs / 3, ks = fs % 3;
        int n = Tg * 16 + (lane & 15);
        int i = (lane >> 4) * 8 + e;
        W3f[idx] = f2bf(w3[n * 96 + i * 3 + ks] * a2s[i]);
    }
    if (threadIdx.x < 64) {
        float s = 0.f;
        for (int i = 0; i < 32; ++i)
            #pragma unroll
            for (int kk = 0; kk < 3; ++kk)
                s = fmaf(w3[threadIdx.x * 96 + i * 3 + kk], d2s[i], s);
        bias3[threadIdx.x] = s;
    }
}

__global__ void __launch_bounds__(256) k3(const unsigned short* __restrict__ p2s,
                                          const unsigned short* __restrict__ W3f,
                                          const float* __restrict__ bias3,
                                          float* __restrict__ act3,
                                          float* __restrict__ stats3,
                                          int B) {
    int j    = blockIdx.y;                   // 0..4
    int wav  = threadIdx.x >> 6;
    int lane = threadIdx.x & 63;
    int msub = wav & 1, nh = wav >> 1;
    int m0   = (blockIdx.x * 2 + msub) * 16;
    int quad = lane >> 4, l15 = lane & 15;
    __shared__ float ls[128];
    if (threadIdx.x < 128) ls[threadIdx.x] = 0.f;
    __syncthreads();
    const short8* Bf = (const short8*)W3f;
    short8 bf[2][3];
    #pragma unroll
    for (int T = 0; T < 2; ++T)
        #pragma unroll
        for (int ks = 0; ks < 3; ++ks)
            bf[T][ks] = Bf[((nh * 2 + T) * 3 + ks) * 64 + lane];
    floatx4 z = {0.f, 0.f, 0.f, 0.f};
    floatx4 acc[2][3];
    #pragma unroll
    for (int T = 0; T < 2; ++T)
        #pragma unroll
        for (int l = 0; l < 3; ++l) acc[T][l] = z;
    #pragma unroll
    for (int ks = 0; ks < 3; ++ks) {
        int jj = j + ks;
        #pragma unroll
        for (int l = 0; l < 3; ++l) {
            const short8* ap =
                (const short8*)(p2s + ((size_t)(jj * 4 + l) * B + m0 + l15) * 32) + quad;
            short8 a = *ap;
            #pragma unroll
            for (int T = 0; T < 2; ++T)
                acc[T][l] = __builtin_amdgcn_mfma_f32_16x16x32_bf16(a, bf[T][ks],
                                                                    acc[T][l], 0, 0, 0);
        }
    }
    float inv = 1.f / (float)(1 << j);
    int mbase = m0 + quad * 4;
    #pragma unroll
    for (int T = 0; T < 2; ++T) {
        int col = nh * 32 + T * 16 + l15;    // o
        float bias = bias3[col];
        float psum = 0.f, pss = 0.f;
        #pragma unroll
        for (int r = 0; r < 4; ++r) {
            float v = fmaxf(fmaxf(acc[T][0][r], acc[T][1][r]), acc[T][2][r]);
            v = fmaxf((v + bias) * inv, 0.f);
            act3[(size_t)(mbase + r) * 320 + col * 5 + j] = v;
            psum += v; pss += v * v;
        }
        psum += __shfl_xor(psum, 16, 64); pss += __shfl_xor(pss, 16, 64);
        psum += __shfl_xor(psum, 32, 64); pss += __shfl_xor(pss, 32, 64);
        if (quad == 0) {
            atomicAdd(&ls[col], psum);
            atomicAdd(&ls[64 + col], pss);
        }
    }
    __syncthreads();
    if (threadIdx.x < 64) {
        atomicAdd(&stats3[threadIdx.x], ls[threadIdx.x]);
        atomicAdd(&stats3[64 + threadIdx.x], ls[64 + threadIdx.x]);
    }
}

__global__ void __launch_bounds__(256) k4(const float* __restrict__ act3,
                                          const float* __restrict__ g3,
                                          const float* __restrict__ b3,
                                          const float* __restrict__ stats3,
                                          const float* __restrict__ fw1,
                                          const float* __restrict__ fb1,
                                          const float* __restrict__ fw2,
                                          const float* __restrict__ fb2,
                                          const float* __restrict__ fw3,
                                          const float* __restrict__ fb3,
                                          float* __restrict__ out,
                                          float invN3) {
    int b0 = blockIdx.x * 16;
    int bl = threadIdx.x >> 4, f = threadIdx.x & 15;
    __shared__ float a3s[64], d3s[64];
    if (threadIdx.x < 64) {
        int i = threadIdx.x;
        float mu  = stats3[i] * invN3;
        float var = stats3[64 + i] * invN3 - mu * mu;
        float rsg = rsqrtf(var + EPS);
        a3s[i] = g3[i] * rsg;
        d3s[i] = b3[i] - mu * a3s[i];
    }
    __syncthreads();
    int b = b0 + bl;
    const float* ab = act3 + (size_t)b * 320;
    float hacc[4] = {fb1[f], 0.f, 0.f, 0.f};   // 4 independent chains
    for (int o = 0; o < 64; o += 4) {
        #pragma unroll
        for (int u = 0; u < 4; ++u) {
            float ao = a3s[o + u], dd = d3s[o + u];
            #pragma unroll
            for (int jj = 0; jj < 5; ++jj) {
                int n = (o + u) * 5 + jj;
                hacc[u] = fmaf(fw1[f * 320 + n], fmaf(ao, ab[n], dd), hacc[u]);
            }
        }
    }
    float h1 = (hacc[0] + hacc[1]) + (hacc[2] + hacc[3]);
    __shared__ float buf[16 * 17];
    buf[bl * 17 + f] = h1;
    __syncthreads();
    float h2 = fb2[f];
    #pragma unroll
    for (int n = 0; n < 16; ++n) h2 = fmaf(fw2[f * 16 + n], buf[bl * 17 + n], h2);
    __syncthreads();
    buf[bl * 17 + f] = h2;
    __syncthreads();
    float o1 = fb3[f];
    #pragma unroll
    for (int n = 0; n < 16; ++n) o1 = fmaf(fw3[f * 16 + n], buf[bl * 17 + n], o1);
    out[(size_t)b * 17 + f] = o1;
    if (f == 0) {
        float o2 = fb3[16];
        #pragma unroll
        for (int n = 0; n < 16; ++n) o2 = fmaf(fw3[16 * 16 + n], buf[bl * 17 + n], o2);
        out[(size_t)b * 17 + 16] = o2;
    }
}

extern "C" void kernel_launch(void* const* d_in, const int* in_sizes, int n_in,
                              void* d_out, int out_size, void* d_ws, size_t ws_size,
                              hipStream_t stream) {
    (void)n_in; (void)out_size; (void)ws_size;
    const float* x   = (const float*)d_in[0];
    const float* w1  = (const float*)d_in[1];
    const float* w2  = (const float*)d_in[2];
    const float* w3  = (const float*)d_in[3];
    const float* g1  = (const float*)d_in[4];
    const float* b1  = (const float*)d_in[5];
    const float* g2  = (const float*)d_in[6];
    const float* b2  = (const float*)d_in[7];
    const float* g3  = (const float*)d_in[8];
    const float* b3  = (const float*)d_in[9];
    const float* fw1 = (const float*)d_in[10];
    const float* fb1 = (const float*)d_in[11];
    const float* fw2 = (const float*)d_in[12];
    const float* fb2 = (const float*)d_in[13];
    const float* fw3 = (const float*)d_in[14];
    const float* fb3 = (const float*)d_in[15];
    float* out = (float*)d_out;

    int B = in_sizes[0] / 96;                 // 4096

    char* wsb = (char*)d_ws;
    float*          stats  = (float*)wsb;                     // 256 f
    unsigned short* W1f    = (unsigned short*)(wsb + 1024);   // 221184 us
    unsigned short* xf     = W1f + 221184;                    // B*96 us
    unsigned short* W2f    = xf + (size_t)B * 96;             // 688128 us
    float*          bias2  = (float*)(W2f + 688128);          // 1792 f
    unsigned short* W3f    = (unsigned short*)(bias2 + 1792); // 6144 us
    float*          bias3  = (float*)(W3f + 6144);            // 64 f
    unsigned short* p1     = (unsigned short*)(bias3 + 64);   // B*1152 us
    unsigned short* p2s    = p1 + (size_t)B * 1152;           // B*896 us
    float*          act3   = (float*)(p2s + (size_t)B * 896); // B*320 f

    float* stats1 = stats;
    float* stats2 = stats + 32;
    float* stats3 = stats + 96;

    float invN1 = 1.f / (float)(B * 72);
    float invN2 = 1.f / (float)(B * 28);
    float invN3 = 1.f / (float)(B * 5);

    int nxf = B * 96;
    int setup_threads = 221184 + nxf;
    k_setup<<<(setup_threads + 255) / 256, 256, 0, stream>>>(w1, x, W1f, xf, stats, nxf);
    k1<<<dim3(B / 32, 9), 256, 0, stream>>>(xf, W1f, p1, stats1);
    k_bias<<<7 * 256, 384, 0, stream>>>(w2, g1, b1, stats1, W2f, bias2, invN1);
    k2<<<dim3(B / 32, 7), 256, 0, stream>>>(p1, W2f, bias2, p2s, stats2, B);
    k_w3<<<1, 256, 0, stream>>>(w3, g2, b2, stats2, W3f, bias3, invN2);
    k3<<<dim3(B / 32, 5), 256, 0, stream>>>(p2s, W3f, bias3, act3, stats3, B);
    k4<<<B / 16, 256, 0, stream>>>(act3, g3, b3, stats3, fw1, fb1, fw2, fb2, fw3, fb3,
                                   out, invN3);
}